// Round 16
// baseline (180.749 us; speedup 1.0000x reference)
//
#include <hip/hip_runtime.h>
#include <hip/hip_bf16.h>
#include <stdint.h>

typedef __attribute__((ext_vector_type(8))) short bf16x8;
typedef __attribute__((ext_vector_type(4))) float f32x4;
typedef __attribute__((ext_vector_type(4))) unsigned short us4;

#define AS1C(p) ((const __attribute__((address_space(1))) void*)(p))
#define AS3(p)  ((__attribute__((address_space(3))) void*)(p))

// raw v_exp_f32 (2^x). exp2f (libm) lowers to OCML with denormal fixup — slow.
#if __has_builtin(__builtin_amdgcn_exp2f)
#define EXP2(x) __builtin_amdgcn_exp2f(x)
#else
#define EXP2(x) __expf((x) * 0.69314718f)
#endif

#define MAX3(a,b,c) fmaxf(fmaxf((a),(b)),(c))   // clang fuses to v_max3_f32

// compiler-fence + raw barrier discipline for counted-vmcnt pipelines.
#define SBAR() __builtin_amdgcn_sched_barrier(0)
#define BARRIER() { SBAR(); __builtin_amdgcn_s_barrier(); SBAR(); }
#define WAIT_LGKM0() { asm volatile("s_waitcnt lgkmcnt(0)" ::: "memory"); SBAR(); }
#define WAIT_VM2() { asm volatile("s_waitcnt vmcnt(2)" ::: "memory"); SBAR(); }
#define WAIT_VM0() { asm volatile("s_waitcnt vmcnt(0)" ::: "memory"); SBAR(); }

static __device__ __forceinline__ unsigned short f2b(float f) {
  union { __hip_bfloat16 h; unsigned short u; } cv;
  cv.h = __float2bfloat16(f);
  return cv.u;
}

// T12 recipe: v_cvt_pk_bf16_f32 has no builtin on gfx950 — inline asm.
static __device__ __forceinline__ unsigned int cvtpk(float a, float b) {
  unsigned int r;
  asm("v_cvt_pk_bf16_f32 %0, %1, %2" : "=v"(r) : "v"(a), "v"(b));
  return r;
}

// ---------------------------------------------------------------------------
// Fused conversions: one dispatch, blockIdx ranges select the job.
// ---------------------------------------------------------------------------
__global__ __launch_bounds__(256) void conv_all_kernel(
    const float* __restrict__ x,  unsigned short* __restrict__ xb,
    const float* __restrict__ Wq, const float* __restrict__ Wk,
    const float* __restrict__ Wv, unsigned short* __restrict__ WqkvT,
    const float* __restrict__ Wo, unsigned short* __restrict__ WoT) {
  __shared__ float tile[64][65];
  const int bid = blockIdx.x;
  const int t = threadIdx.x;

  if (bid < 8192) {                       // ---- conv_x ----
    int i = bid * 256 + t;                // n4 = 2097152 exactly = 8192*256
    float4 v = ((const float4*)x)[i];
    us4 r = { f2b(v.x), f2b(v.y), f2b(v.z), f2b(v.w) };
    *(us4*)&xb[(size_t)i * 4] = r;
    return;
  }

  const int c  = t & 63;
  const int r0 = t >> 6;                  // 0..3

  if (bid < 8960) {                       // ---- conv_wqkv ----
    int b2 = bid - 8192;                  // 768 blocks
    int which = b2 >> 8;
    int h  = (b2 >> 4) & 15;
    int dt = b2 & 15;
    const float* W = (which == 0) ? Wq : (which == 1 ? Wk : Wv);
    const float* src = W + (size_t)h * 65536 + (size_t)dt * 64 * 64;
#pragma unroll
    for (int it = 0; it < 16; ++it) {
      int r = r0 + it * 4;
      tile[r][c] = src[r * 64 + c];       // tile[d_local][c_local]
    }
    __syncthreads();
    const size_t n0 = (size_t)which * 1024 + h * 64;
    const int d0 = dt * 64;
#pragma unroll
    for (int it = 0; it < 16; ++it) {
      int cc = r0 + it * 4;               // c_local (output row)
      WqkvT[(n0 + cc) * 1024 + d0 + c] = f2b(tile[c][cc]);
    }
    return;
  }

  {                                       // ---- conv_wo ----
    int b2 = bid - 8960;                  // 256 blocks
    int kt = b2 >> 4, nt = b2 & 15;
    const float* src = Wo + (size_t)(kt * 64) * 1024 + nt * 64;
#pragma unroll
    for (int it = 0; it < 16; ++it) {
      int r = r0 + it * 4;
      tile[r][c] = src[(size_t)r * 1024 + c];   // tile[k_local][n_local]
    }
    __syncthreads();
#pragma unroll
    for (int it = 0; it < 16; ++it) {
      int cc = r0 + it * 4;                     // n_local (output row)
      WoT[((size_t)nt * 64 + cc) * 1024 + kt * 64 + c] = f2b(tile[c][cc]);
    }
  }
}

// ---------------------------------------------------------------------------
// GEMM 1: C[8192][3072] = x_bf16 [8192][1024] * WqkvT[3072][1024]^T
// Ring-3 counted-vmcnt pipeline + T5 setprio around the MFMA cluster.
// Read-side 2-way bank swizzle: src chunk c^((row>>1)&3), read hi^((l15>>1)&3).
// XCD-relabeled grid (bijective, 1536 = 8*192). 8 waves, 32x64 C per wave.
// epilogue: Q pre-scaled by (1/8)*log2(e); K straight; V transposed.
// ---------------------------------------------------------------------------
__global__ __launch_bounds__(512) void gemm_qkv_kernel(
    const unsigned short* __restrict__ A,
    const unsigned short* __restrict__ Bt,
    unsigned short* __restrict__ Q,
    unsigned short* __restrict__ Ko,
    unsigned short* __restrict__ Vt) {
  __shared__ __align__(16) unsigned short sL[3 * 8192];  // 48KB: 3 x (A[128][32] | B[128][32])
  const int tid  = threadIdx.x;
  const int lane = tid & 63;
  const int wid  = tid >> 6;              // 0..7
  const int l15 = lane & 15, hi = lane >> 4;
  const int wr = wid >> 1, wc = wid & 1;
  const int n0 = blockIdx.y * 24 + blockIdx.x;        // 1536 blocks
  const int n1 = (n0 & 7) * 192 + (n0 >> 3);          // XCD-contiguous relabel
  const int brow = (n1 / 24) * 128;
  const int bcol = (n1 % 24) * 128;
  const int K = 1024;

  f32x4 acc[2][4] = {};

  // staging: thread = chunk tid of [128 rows][4 x 16B]; source pre-swizzled
  const int srow = tid >> 2;
  const int suc  = (tid & 3) ^ ((srow >> 1) & 3);
  const unsigned short* gaS = A  + (size_t)(brow + srow) * K + suc * 8;
  const unsigned short* gbS = Bt + (size_t)(bcol + srow) * K + suc * 8;
  const int wofs = wid * 512;             // wave-uniform LDS base (shorts)

  // frag-read swizzle (row>>1)&3 == (l15>>1)&3 for all frag rows
  const int ck = (hi ^ ((l15 >> 1) & 3)) * 8;
  const int arow0 = wr * 32 + l15;        // + mi*16
  const int brow0 = wc * 64 + l15;        // + ni*16

#define QKV_STAGE(u) { \
    unsigned short* dst_ = sL + ((u) % 3) * 8192 + wofs; \
    __builtin_amdgcn_global_load_lds(AS1C(gaS + (u) * 32), AS3(dst_), 16, 0, 0); \
    __builtin_amdgcn_global_load_lds(AS1C(gbS + (u) * 32), AS3(dst_ + 4096), 16, 0, 0); \
  }

  QKV_STAGE(0); QKV_STAGE(1);
  WAIT_VM2(); BARRIER();

  for (int t = 0; t < 32; ++t) {
    if (t < 30) QKV_STAGE(t + 2);
    const unsigned short* sA_ = sL + (t % 3) * 8192;
    const unsigned short* sB_ = sA_ + 4096;
    bf16x8 af[2], bfr[4];
#pragma unroll
    for (int mi = 0; mi < 2; ++mi)
      af[mi] = *(const bf16x8*)&sA_[(arow0 + mi * 16) * 32 + ck];
#pragma unroll
    for (int ni = 0; ni < 4; ++ni)
      bfr[ni] = *(const bf16x8*)&sB_[(brow0 + ni * 16) * 32 + ck];
    WAIT_LGKM0();
    __builtin_amdgcn_s_setprio(1);
#pragma unroll
    for (int mi = 0; mi < 2; ++mi)
#pragma unroll
      for (int ni = 0; ni < 4; ++ni)
        acc[mi][ni] = __builtin_amdgcn_mfma_f32_16x16x32_bf16(af[mi], bfr[ni], acc[mi][ni], 0, 0, 0);
    __builtin_amdgcn_s_setprio(0);
    if (t < 30) { WAIT_VM2(); } else { WAIT_VM0(); }
    BARRIER();
  }
#undef QKV_STAGE

#pragma unroll
  for (int mi = 0; mi < 2; ++mi) {
    int row0 = brow + wr * 32 + mi * 16 + hi * 4;
    int b = row0 >> 11, s0 = row0 & 2047;
#pragma unroll
    for (int ni = 0; ni < 4; ++ni) {
      int col = bcol + wc * 64 + ni * 16 + l15;
      int which = col >> 10;      // block-uniform
      int h  = (col >> 6) & 15;
      int kk = col & 63;
      if (which == 2) {
        us4 pk = { f2b(acc[mi][ni][0]), f2b(acc[mi][ni][1]),
                   f2b(acc[mi][ni][2]), f2b(acc[mi][ni][3]) };
        *(us4*)&Vt[((size_t)(b * 16 + h) * 64 + kk) * 2048 + s0] = pk;
      } else {
        unsigned short* dst = (which == 0) ? Q : Ko;
        // Q: fold 1/sqrt(dk) * log2(e) so softmax uses raw v_exp (2^x)
        float scl = (which == 0) ? 0.18033688f : 1.0f;
#pragma unroll
        for (int j = 0; j < 4; ++j)
          dst[((size_t)(b * 16 + h) * 2048 + (s0 + j)) * 64 + kk] = f2b(acc[mi][ni][j] * scl);
      }
    }
  }
}

// ---------------------------------------------------------------------------
// GEMM 2: out[8192][1024] (fp32) = O_bf16 [8192][1024] * WoT[1024][1024]^T
// Same ring-3 counted-vmcnt structure + T5 setprio. XCD relabel (512 = 8*64).
// ---------------------------------------------------------------------------
__global__ __launch_bounds__(512) void gemm_out_kernel(
    const unsigned short* __restrict__ A,
    const unsigned short* __restrict__ Bt,
    float* __restrict__ out) {
  __shared__ __align__(16) unsigned short sL[3 * 8192];
  const int tid  = threadIdx.x;
  const int lane = tid & 63;
  const int wid  = tid >> 6;
  const int l15 = lane & 15, hi = lane >> 4;
  const int wr = wid >> 1, wc = wid & 1;
  const int n0 = blockIdx.y * 8 + blockIdx.x;         // 512 blocks
  const int n1 = (n0 & 7) * 64 + (n0 >> 3);           // XCD-contiguous relabel
  const int brow = (n1 >> 3) * 128;
  const int bcol = (n1 & 7) * 128;
  const int K = 1024;

  f32x4 acc[2][4] = {};

  const int srow = tid >> 2;
  const int suc  = (tid & 3) ^ ((srow >> 1) & 3);
  const unsigned short* gaS = A  + (size_t)(brow + srow) * K + suc * 8;
  const unsigned short* gbS = Bt + (size_t)(bcol + srow) * K + suc * 8;
  const int wofs = wid * 512;

  const int ck = (hi ^ ((l15 >> 1) & 3)) * 8;
  const int arow0 = wr * 32 + l15;
  const int brow0 = wc * 64 + l15;

#define OUT_STAGE(u) { \
    unsigned short* dst_ = sL + ((u) % 3) * 8192 + wofs; \
    __builtin_amdgcn_global_load_lds(AS1C(gaS + (u) * 32), AS3(dst_), 16, 0, 0); \
    __builtin_amdgcn_global_load_lds(AS1C(gbS + (u) * 32), AS3(dst_ + 4096), 16, 0, 0); \
  }

  OUT_STAGE(0); OUT_STAGE(1);
  WAIT_VM2(); BARRIER();

  for (int t = 0; t < 32; ++t) {
    if (t < 30) OUT_STAGE(t + 2);
    const unsigned short* sA_ = sL + (t % 3) * 8192;
    const unsigned short* sB_ = sA_ + 4096;
    bf16x8 af[2], bfr[4];
#pragma unroll
    for (int mi = 0; mi < 2; ++mi)
      af[mi] = *(const bf16x8*)&sA_[(arow0 + mi * 16) * 32 + ck];
#pragma unroll
    for (int ni = 0; ni < 4; ++ni)
      bfr[ni] = *(const bf16x8*)&sB_[(brow0 + ni * 16) * 32 + ck];
    WAIT_LGKM0();
    __builtin_amdgcn_s_setprio(1);
#pragma unroll
    for (int mi = 0; mi < 2; ++mi)
#pragma unroll
      for (int ni = 0; ni < 4; ++ni)
        acc[mi][ni] = __builtin_amdgcn_mfma_f32_16x16x32_bf16(af[mi], bfr[ni], acc[mi][ni], 0, 0, 0);
    __builtin_amdgcn_s_setprio(0);
    if (t < 30) { WAIT_VM2(); } else { WAIT_VM0(); }
    BARRIER();
  }
#undef OUT_STAGE

#pragma unroll
  for (int mi = 0; mi < 2; ++mi) {
    int row0 = brow + wr * 32 + mi * 16 + hi * 4;
#pragma unroll
    for (int ni = 0; ni < 4; ++ni) {
      int col = bcol + wc * 64 + ni * 16 + l15;
#pragma unroll
      for (int j = 0; j < 4; ++j)
        out[(size_t)(row0 + j) * 1024 + col] = acc[mi][ni][j];
    }
  }
}

// ---------------------------------------------------------------------------
// Flash attention (EXACT R14 revert — R15's hoisted-QK variant failed
// correctness via a codegen/scheduling hazard; this version is verified
// at ~87 us, absmax 2.7e-4):
// 512-thread / 8-wave blocks, 32 q-rows/wave, grid 512 = 2/CU, DMA-dbuf
// staging, 1 barrier/tile, -m folded into MFMA acc init, l via ones-MFMA,
// swapped QK^T + defer-max + exp2-folded softmax + cvt_pk P-pack + max3 +
// rule-#21 XOR swizzle. XCD relabel: 8 consecutive bh per XCD.
// ---------------------------------------------------------------------------
__global__ __launch_bounds__(512) void attn_kernel(
    const unsigned short* __restrict__ Q,
    const unsigned short* __restrict__ K,
    const unsigned short* __restrict__ Vt,
    unsigned short* __restrict__ O) {
  __shared__ __align__(16) unsigned short sK[2][64 * 64];   // dbuf, XOR-swizzled
  __shared__ __align__(16) unsigned short sVt[2][64 * 64];  // dbuf, XOR-swizzled
  __shared__ __align__(16) unsigned short sP[16][16 * 72];  // [w*2+mi][q][key] pad 72

  const int tid = threadIdx.x, lane = tid & 63, w = tid >> 6;   // w = 0..7
  const int l15 = lane & 15, hi = lane >> 4;
  // bijective relabel: grid (8, 64); xcd = n&7 -> 8 consecutive bh per XCD
  const int n = blockIdx.x + (blockIdx.y << 3);
  const int bh = (n & 7) * 8 + (n >> 6);
  const int qx = (n >> 3) & 7;
  const int qb = qx * 256;
  const unsigned short* Qp  = Q  + (size_t)bh * 131072;
  const unsigned short* Kp  = K  + (size_t)bh * 131072;
  const unsigned short* Vtp = Vt + (size_t)bh * 131072;

  // per-wave 32 q-rows (mi = 0,1)
  bf16x8 qf[2][2];
#pragma unroll
  for (int mi = 0; mi < 2; ++mi) {
    int qrow = qb + w * 32 + mi * 16 + l15;
    qf[mi][0] = *(const bf16x8*)&Qp[(size_t)qrow * 64 + hi * 8];
    qf[mi][1] = *(const bf16x8*)&Qp[(size_t)qrow * 64 + 32 + hi * 8];
  }

  // ones fragment for the l-sum MFMA (bf16 1.0 = 0x3F80)
  bf16x8 ones;
#pragma unroll
  for (int j = 0; j < 8; ++j) ones[j] = (short)0x3F80;

  f32x4 o[2][4] = {};
  f32x4 lacc[2] = {};              // lacc[mi][j] = running l for q = hi*4+j
  float m_[2] = { 0.f, 0.f };      // defer-max: absolute running max (log2 units)

  // staging geometry: wave w owns rows w*8 .. w*8+7 of the 64-row tile.
  const int lrow = lane >> 3;                 // 0..7
  const int uch  = (lane & 7) ^ lrow;         // pre-swizzled global chunk
  const unsigned short* kg = Kp  + (size_t)(w * 8 + lrow) * 64   + uch * 8;
  const unsigned short* vg = Vtp + (size_t)(w * 8 + lrow) * 2048 + uch * 8;
  unsigned short* dK0 = &sK[0][w * 512];      // wave-uniform LDS bases
  unsigned short* dK1 = &sK[1][w * 512];
  unsigned short* dV0 = &sVt[0][w * 512];
  unsigned short* dV1 = &sVt[1][w * 512];

  // read-side swizzle constants
  const int x7 = l15 & 7;
  const int ck0 = (hi ^ x7) * 8;
  const int ck1 = ((hi + 4) ^ x7) * 8;

  // prologue: tile 0 -> buf 0
  __builtin_amdgcn_global_load_lds(AS1C(kg), AS3(dK0), 16, 0, 0);
  __builtin_amdgcn_global_load_lds(AS1C(vg), AS3(dV0), 16, 0, 0);
  __syncthreads();

  for (int kt = 0; kt < 32; ++kt) {
    const int cur = kt & 1;
    if (kt < 31) {                 // issue next tile's DMA into the other buf
      kg += 4096; vg += 64;
      __builtin_amdgcn_global_load_lds(AS1C(kg), AS3(cur ? dK0 : dK1), 16, 0, 0);
      __builtin_amdgcn_global_load_lds(AS1C(vg), AS3(cur ? dV0 : dV1), 16, 0, 0);
    }
    const unsigned short* sKc  = &sK[cur][0];
    const unsigned short* sVtc = &sVt[cur][0];

#pragma unroll
    for (int mi = 0; mi < 2; ++mi) {
      // S^T - m = K Q^T + (-m) : acc init carries the bias
      const float mneg = -m_[mi];
      f32x4 sc[4] = { { mneg, mneg, mneg, mneg }, { mneg, mneg, mneg, mneg },
                      { mneg, mneg, mneg, mneg }, { mneg, mneg, mneg, mneg } };
      __builtin_amdgcn_s_setprio(1);
#pragma unroll
      for (int ni = 0; ni < 4; ++ni) {
        bf16x8 kf0 = *(const bf16x8*)&sKc[(ni * 16 + l15) * 64 + ck0];
        bf16x8 kf1 = *(const bf16x8*)&sKc[(ni * 16 + l15) * 64 + ck1];
        sc[ni] = __builtin_amdgcn_mfma_f32_16x16x32_bf16(kf0, qf[mi][0], sc[ni], 0, 0, 0);
        sc[ni] = __builtin_amdgcn_mfma_f32_16x16x32_bf16(kf1, qf[mi][1], sc[ni], 0, 0, 0);
      }
      __builtin_amdgcn_s_setprio(0);

      // per-lane biased tile max via max3 (guard only)
      float t0 = MAX3(sc[0][0], sc[0][1], sc[0][2]);
      float t1 = MAX3(sc[0][3], sc[1][0], sc[1][1]);
      float t2 = MAX3(sc[1][2], sc[1][3], sc[2][0]);
      float t3 = MAX3(sc[2][1], sc[2][2], sc[2][3]);
      float t4 = MAX3(sc[3][0], sc[3][1], sc[3][2]);
      float pmax = fmaxf(MAX3(t0, t1, t2), MAX3(t3, t4, sc[3][3]));

      // T13: rescale only if biased P would exceed 2^8 (never fires normally)
      if (!__all(pmax <= 8.0f)) {
        pmax = fmaxf(pmax, __shfl_xor(pmax, 16));     // row-uniform biased max
        pmax = fmaxf(pmax, __shfl_xor(pmax, 32));
        float delta = fmaxf(pmax, 0.f);               // mnew - mold
#pragma unroll
        for (int j = 0; j < 4; ++j) {
          float dj = __shfl(delta, hi * 4 + j);
          float aj = EXP2(-dj);
          lacc[mi][j] *= aj;
#pragma unroll
          for (int ni = 0; ni < 4; ++ni) o[mi][ni][j] *= aj;
        }
#pragma unroll
        for (int ni = 0; ni < 4; ++ni)
#pragma unroll
          for (int r = 0; r < 4; ++r) sc[ni][r] -= delta;
        m_[mi] += delta;
      }

      f32x4 p4[4];
#pragma unroll
      for (int ni = 0; ni < 4; ++ni)
#pragma unroll
        for (int r = 0; r < 4; ++r)
          p4[ni][r] = EXP2(sc[ni][r]);

      // P -> per-wave LDS [q=l15][key]; v_cvt_pk_bf16_f32 (1 inst / 2 vals)
      unsigned short* pb = &sP[w * 2 + mi][l15 * 72];
#pragma unroll
      for (int ni = 0; ni < 4; ++ni) {
        uint2 pk = { cvtpk(p4[ni][0], p4[ni][1]), cvtpk(p4[ni][2], p4[ni][3]) };
        *(uint2*)&pb[ni * 16 + hi * 4] = pk;
      }
    }

    // O += P V ; lacc += P * ones (l on the matrix pipe)
    bf16x8 pa[2][2];
#pragma unroll
    for (int mi = 0; mi < 2; ++mi) {
      pa[mi][0] = *(const bf16x8*)&sP[w * 2 + mi][l15 * 72 + hi * 8];
      pa[mi][1] = *(const bf16x8*)&sP[w * 2 + mi][l15 * 72 + 32 + hi * 8];
    }
    __builtin_amdgcn_s_setprio(1);
#pragma unroll
    for (int mi = 0; mi < 2; ++mi) {
      lacc[mi] = __builtin_amdgcn_mfma_f32_16x16x32_bf16(pa[mi][0], ones, lacc[mi], 0, 0, 0);
      lacc[mi] = __builtin_amdgcn_mfma_f32_16x16x32_bf16(pa[mi][1], ones, lacc[mi], 0, 0, 0);
    }
#pragma unroll
    for (int ni = 0; ni < 4; ++ni) {
      bf16x8 vf0 = *(const bf16x8*)&sVtc[(ni * 16 + l15) * 64 + ck0];
      bf16x8 vf1 = *(const bf16x8*)&sVtc[(ni * 16 + l15) * 64 + ck1];
#pragma unroll
      for (int mi = 0; mi < 2; ++mi) {
        o[mi][ni] = __builtin_amdgcn_mfma_f32_16x16x32_bf16(pa[mi][0], vf0, o[mi][ni], 0, 0, 0);
        o[mi][ni] = __builtin_amdgcn_mfma_f32_16x16x32_bf16(pa[mi][1], vf1, o[mi][ni], 0, 0, 0);
      }
    }
    __builtin_amdgcn_s_setprio(0);

    __syncthreads();               // publish next tile (vmcnt drained here)
  }

  // epilogue: lacc[mi][j] already holds the full l for q = hi*4+j — no shuffles
  const int b = bh >> 4, h = bh & 15;
#pragma unroll
  for (int mi = 0; mi < 2; ++mi) {
#pragma unroll
    for (int j = 0; j < 4; ++j) {
      float inv = 1.0f / lacc[mi][j];
      int row = qb + w * 32 + mi * 16 + hi * 4 + j;
#pragma unroll
      for (int ni = 0; ni < 4; ++ni)
        O[((size_t)b * 2048 + row) * 1024 + h * 64 + ni * 16 + l15] = f2b(o[mi][ni][j] * inv);
    }
  }
}

// ---------------------------------------------------------------------------
extern "C" void kernel_launch(void* const* d_in, const int* in_sizes, int n_in,
                              void* d_out, int out_size, void* d_ws, size_t ws_size,
                              hipStream_t stream) {
  const float* x  = (const float*)d_in[0];
  const float* Wq = (const float*)d_in[1];
  const float* Wk = (const float*)d_in[2];
  const float* Wv = (const float*)d_in[3];
  const float* Wo = (const float*)d_in[4];
  float* out = (float*)d_out;

  char* w = (char*)d_ws;
  unsigned short* xb   = (unsigned short*)(w);                       // 16 MB
  unsigned short* wqkv = (unsigned short*)(w + 16777216);            //  6 MB
  unsigned short* wo   = (unsigned short*)(w + 23068672);            //  2 MB
  unsigned short* Qb   = (unsigned short*)(w + 25165824);            // 16 MB
  unsigned short* Kb   = (unsigned short*)(w + 41943040);            // 16 MB
  unsigned short* Vtb  = (unsigned short*)(w + 58720256);            // 16 MB (V transposed)
  unsigned short* Ob   = (unsigned short*)(w + 75497472);            // 16 MB

  conv_all_kernel<<<9216, 256, 0, stream>>>(x, xb, Wq, Wk, Wv, wqkv, Wo, wo);
  gemm_qkv_kernel<<<dim3(24, 64), 512, 0, stream>>>(xb, wqkv, Qb, Kb, Vtb);
  attn_kernel<<<dim3(8, 64), 512, 0, stream>>>(Qb, Kb, Vtb, Ob);
  gemm_out_kernel<<<dim3(8, 64), 512, 0, stream>>>(Ob, wo, out);
}